// Round 1
// baseline (23422.328 us; speedup 1.0000x reference)
//
#include <hip/hip_runtime.h>

#define B_ 128
#define T_ 512
#define D_ 256
#define H_ 512

typedef __bf16 bf16x8 __attribute__((ext_vector_type(8)));
typedef float  f32x4  __attribute__((ext_vector_type(4)));

// h exchange buffers: double-buffered, pre-split into bf16 hi/lo so consumers
// can load straight into MFMA A-fragments. 4*128*512*2B = 512 KB total.
__device__ __align__(16) __bf16 g_hhi[2][B_ * H_];
__device__ __align__(16) __bf16 g_hlo[2][B_ * H_];

__device__ inline float sigmoidf_(float v) { return 1.f / (1.f + __expf(-v)); }
__device__ inline float tanhf_(float v)    { return 1.f - 2.f / (__expf(2.f * v) + 1.f); }

// Persistent LSTM kernel.
// Grid: 256 blocks = 64 gate-groups (gg: 8 hidden units each) x 4 batch-groups (bg: 32 rows).
// Block: 256 threads = 4 waves; wave w owns K-slice [w*64,w*64+64) of D and [w*128,w*128+128) of H.
// Weights live in per-wave B-fragment registers (bf16 hi/lo) for the whole kernel.
__global__ __launch_bounds__(256, 1)
void lstm_persistent(const float* __restrict__ x,
                     const float* __restrict__ Wih,
                     const float* __restrict__ Whh,
                     const float* __restrict__ bih,
                     const float* __restrict__ bhh,
                     float* __restrict__ out,
                     unsigned int* __restrict__ bar)
{
    const int tid  = threadIdx.x;
    const int wv   = tid >> 6;
    const int lane = tid & 63;
    const int gg   = blockIdx.x & 63;   // gate group: hidden units [gg*8, gg*8+8)
    const int bg   = blockIdx.x >> 6;   // batch group: rows [bg*32, bg*32+32)

    const int lm = lane & 15;           // M/N index inside a 16x16 MFMA tile
    const int lq = lane >> 4;           // k-quad (k offset = lq*8)

    // ---- Load weight B-fragments (once, reused for all 512 steps) ----
    // Block's 32 gate rows: r_g = type*8 + j  ->  global row type*512 + gg*8 + j.
    bf16x8 wih_hi[2][2], wih_lo[2][2];  // [kt][gt], k = wv*64 + kt*32 + lq*8
    bf16x8 whh_hi[4][2], whh_lo[4][2];  // [kt][gt], k = wv*128 + kt*32 + lq*8

    for (int gt = 0; gt < 2; ++gt) {
        const int rg   = gt * 16 + lm;             // 0..31
        const int type = rg >> 3;
        const int j    = rg & 7;
        const int grow = type * 512 + gg * 8 + j;  // global gate row
#pragma unroll
        for (int kt = 0; kt < 2; ++kt) {
            const int k = wv * 64 + kt * 32 + lq * 8;
            const float* p = Wih + (size_t)grow * D_ + k;
            bf16x8 hi, lo;
#pragma unroll
            for (int e = 0; e < 8; ++e) {
                float v = p[e];
                __bf16 h1 = (__bf16)v;
                hi[e] = h1;
                lo[e] = (__bf16)(v - (float)h1);
            }
            wih_hi[kt][gt] = hi; wih_lo[kt][gt] = lo;
        }
#pragma unroll
        for (int kt = 0; kt < 4; ++kt) {
            const int k = wv * 128 + kt * 32 + lq * 8;
            const float* p = Whh + (size_t)grow * H_ + k;
            bf16x8 hi, lo;
#pragma unroll
            for (int e = 0; e < 8; ++e) {
                float v = p[e];
                __bf16 h1 = (__bf16)v;
                hi[e] = h1;
                lo[e] = (__bf16)(v - (float)h1);
            }
            whh_hi[kt][gt] = hi; whh_lo[kt][gt] = lo;
        }
    }

    // ---- Pointwise thread mapping: (hidden j = tid&7, batch b = tid>>3) ----
    const int pj = tid & 7;
    const int pb = tid >> 3;
    float bias[4];
#pragma unroll
    for (int tp = 0; tp < 4; ++tp) {
        const int r = tp * 512 + gg * 8 + pj;
        bias[tp] = bih[r] + bhh[r];
    }
    float c = 0.f;

    __shared__ __align__(16) float gp[4][32][36];  // [wave][gate row][batch] partials, padded

    const int bglob0 = bg * 32;

    for (int t = 0; t < T_; ++t) {
        f32x4 acc[2][2];
#pragma unroll
        for (int bt = 0; bt < 2; ++bt)
#pragma unroll
            for (int gt = 0; gt < 2; ++gt)
                acc[bt][gt] = (f32x4){0.f, 0.f, 0.f, 0.f};

        // ---- x part: A-fragments straight from global fp32, split hi/lo ----
#pragma unroll
        for (int bt = 0; bt < 2; ++bt) {
            const int brow = bglob0 + bt * 16 + lm;
            const float* pxr = x + ((size_t)brow * T_ + t) * D_;
#pragma unroll
            for (int kt = 0; kt < 2; ++kt) {
                const int k = wv * 64 + kt * 32 + lq * 8;
                const float* p = pxr + k;
                f32x4 v0 = *(const f32x4*)p;
                f32x4 v1 = *(const f32x4*)(p + 4);
                bf16x8 ahi, alo;
#pragma unroll
                for (int e = 0; e < 4; ++e) {
                    __bf16 h1 = (__bf16)v0[e];
                    ahi[e] = h1; alo[e] = (__bf16)(v0[e] - (float)h1);
                    __bf16 h2 = (__bf16)v1[e];
                    ahi[e + 4] = h2; alo[e + 4] = (__bf16)(v1[e] - (float)h2);
                }
#pragma unroll
                for (int gt = 0; gt < 2; ++gt) {
                    acc[bt][gt] = __builtin_amdgcn_mfma_f32_16x16x32_bf16(ahi, wih_hi[kt][gt], acc[bt][gt], 0, 0, 0);
                    acc[bt][gt] = __builtin_amdgcn_mfma_f32_16x16x32_bf16(ahi, wih_lo[kt][gt], acc[bt][gt], 0, 0, 0);
                    acc[bt][gt] = __builtin_amdgcn_mfma_f32_16x16x32_bf16(alo, wih_hi[kt][gt], acc[bt][gt], 0, 0, 0);
                }
            }
        }

        // ---- h part: A-fragments straight from bf16 hi/lo exchange buffers ----
        if (t > 0) {
            const int rbuf = (t + 1) & 1;  // == (t-1)&1
#pragma unroll
            for (int bt = 0; bt < 2; ++bt) {
                const int brow = bglob0 + bt * 16 + lm;
#pragma unroll
                for (int kt = 0; kt < 4; ++kt) {
                    const int k = wv * 128 + kt * 32 + lq * 8;
                    bf16x8 ahi = *(const bf16x8*)&g_hhi[rbuf][(size_t)brow * H_ + k];
                    bf16x8 alo = *(const bf16x8*)&g_hlo[rbuf][(size_t)brow * H_ + k];
#pragma unroll
                    for (int gt = 0; gt < 2; ++gt) {
                        acc[bt][gt] = __builtin_amdgcn_mfma_f32_16x16x32_bf16(ahi, whh_hi[kt][gt], acc[bt][gt], 0, 0, 0);
                        acc[bt][gt] = __builtin_amdgcn_mfma_f32_16x16x32_bf16(ahi, whh_lo[kt][gt], acc[bt][gt], 0, 0, 0);
                        acc[bt][gt] = __builtin_amdgcn_mfma_f32_16x16x32_bf16(alo, whh_hi[kt][gt], acc[bt][gt], 0, 0, 0);
                    }
                }
            }
        }

        // ---- partial sums -> LDS ----
#pragma unroll
        for (int bt = 0; bt < 2; ++bt)
#pragma unroll
            for (int gt = 0; gt < 2; ++gt) {
                const int g  = gt * 16 + lm;
                const int b0 = bt * 16 + lq * 4;  // C/D layout: row = lq*4 + reg
                *(f32x4*)&gp[wv][g][b0] = acc[bt][gt];
            }
        __syncthreads();

        // ---- reduce over waves + pointwise gate math ----
        float gate[4];
#pragma unroll
        for (int tp = 0; tp < 4; ++tp) {
            const int g = tp * 8 + pj;
            gate[tp] = gp[0][g][pb] + gp[1][g][pb] + gp[2][g][pb] + gp[3][g][pb] + bias[tp];
        }
        const float ig = sigmoidf_(gate[0]);
        const float fg = sigmoidf_(gate[1]);
        const float gv = tanhf_(gate[2]);
        const float og = sigmoidf_(gate[3]);
        c = fg * c + ig * gv;
        const float h = og * tanhf_(c);

        const int brow = bglob0 + pb;
        out[((size_t)t * B_ + brow) * H_ + gg * 8 + pj] = h;
        const int wbuf = t & 1;
        const __bf16 hh = (__bf16)h;
        g_hhi[wbuf][(size_t)brow * H_ + gg * 8 + pj] = hh;
        g_hlo[wbuf][(size_t)brow * H_ + gg * 8 + pj] = (__bf16)(h - (float)hh);

        // ---- inter-block barrier among the 64 gate-group blocks of this bg ----
        if (t < T_ - 1) {
            __threadfence();
            __syncthreads();
            if (tid == 0) {
                atomicAdd(&bar[bg * 64], 1u);
                const unsigned int target = 64u * (unsigned int)(t + 1);
                while (__hip_atomic_load(&bar[bg * 64], __ATOMIC_RELAXED,
                                         __HIP_MEMORY_SCOPE_AGENT) < target)
                    __builtin_amdgcn_s_sleep(1);
            }
            __syncthreads();
            __threadfence();
        }
    }
}

extern "C" void kernel_launch(void* const* d_in, const int* in_sizes, int n_in,
                              void* d_out, int out_size, void* d_ws, size_t ws_size,
                              hipStream_t stream) {
    const float* x   = (const float*)d_in[0];
    const float* Wih = (const float*)d_in[1];
    const float* Whh = (const float*)d_in[2];
    const float* bih = (const float*)d_in[3];
    const float* bhh = (const float*)d_in[4];
    float* out = (float*)d_out;
    unsigned int* bar = (unsigned int*)d_ws;

    // barrier counters must start at 0 (ws is poisoned to 0xAA each launch)
    hipMemsetAsync(d_ws, 0, 4096, stream);
    hipLaunchKernelGGL(lstm_persistent, dim3(256), dim3(256), 0, stream,
                       x, Wih, Whh, bih, bhh, out, bar);
}

// Round 2
// 2687.475 us; speedup vs baseline: 8.7154x; 8.7154x over previous
//
#include <hip/hip_runtime.h>

#define B_ 128
#define T_ 512
#define D_ 256
#define H_ 512
#define GG_ 32   // gate groups: 16 hidden units each
#define BG_ 8    // batch groups: 16 rows each

typedef __bf16 bf16x8 __attribute__((ext_vector_type(8)));
typedef float  f32x4  __attribute__((ext_vector_type(4)));
typedef unsigned int u32;
typedef unsigned long long u64;

// h exchange: double-buffered, each element packed as (bf16 hi) | (bf16 lo << 16).
// Accessed ONLY via agent-scope relaxed atomics (sc1, L2-bypass) => no fences needed.
__device__ __align__(16) u32 g_h[2][B_ * H_];

__device__ inline float sigmoidf_(float v) { return 1.f / (1.f + __expf(-v)); }
__device__ inline float tanhf_(float v)    { return 1.f - 2.f / (__expf(2.f * v) + 1.f); }

// Grid: 256 blocks = 32 gate-groups x 8 batch-groups. Block: 256 threads = 4 waves.
// Wave w owns K-slice [w*64,w*64+64) of D and [w*128,w*128+128) of H.
// Each block computes gates for 16 batch rows x 64 gate rows (4 types x 16 units),
// i.e. h/c for a 16x16 (row,unit) tile. Weights stay in registers for all 512 steps.
__global__ __launch_bounds__(256, 1)
void lstm_persistent(const float* __restrict__ x,
                     const float* __restrict__ Wih,
                     const float* __restrict__ Whh,
                     const float* __restrict__ bih,
                     const float* __restrict__ bhh,
                     float* __restrict__ out,
                     u32* __restrict__ bar)
{
    const int tid  = threadIdx.x;
    const int wv   = tid >> 6;
    const int lane = tid & 63;
    const int gg   = blockIdx.x & (GG_ - 1);
    const int bg   = blockIdx.x / GG_;

    const int lm = lane & 15;   // M/N index in 16x16 MFMA tile
    const int lq = lane >> 4;   // k-quad (k offset = lq*8)

    // ---- Weight B-fragments in registers (bf16 hi/lo), loaded once ----
    bf16x8 wih_hi[2][4], wih_lo[2][4];   // [kt][gt], k = wv*64 + kt*32 + lq*8
    bf16x8 whh_hi[4][4], whh_lo[4][4];   // [kt][gt], k = wv*128 + kt*32 + lq*8

    for (int gt = 0; gt < 4; ++gt) {
        const int grow = gt * 512 + gg * 16 + lm;   // global gate row (type=gt, unit=gg*16+lm)
#pragma unroll
        for (int kt = 0; kt < 2; ++kt) {
            const float* p = Wih + (size_t)grow * D_ + wv * 64 + kt * 32 + lq * 8;
            bf16x8 hi, lo;
#pragma unroll
            for (int e = 0; e < 8; ++e) {
                float v = p[e];
                __bf16 h1 = (__bf16)v;
                hi[e] = h1; lo[e] = (__bf16)(v - (float)h1);
            }
            wih_hi[kt][gt] = hi; wih_lo[kt][gt] = lo;
        }
#pragma unroll
        for (int kt = 0; kt < 4; ++kt) {
            const float* p = Whh + (size_t)grow * H_ + wv * 128 + kt * 32 + lq * 8;
            bf16x8 hi, lo;
#pragma unroll
            for (int e = 0; e < 8; ++e) {
                float v = p[e];
                __bf16 h1 = (__bf16)v;
                hi[e] = h1; lo[e] = (__bf16)(v - (float)h1);
            }
            whh_hi[kt][gt] = hi; whh_lo[kt][gt] = lo;
        }
    }

    // ---- Pointwise mapping: unit pj = tid&15, batch row pb = tid>>4 ----
    const int pj = tid & 15;
    const int pb = tid >> 4;
    float bias[4];
#pragma unroll
    for (int tp = 0; tp < 4; ++tp) {
        const int r = tp * 512 + gg * 16 + pj;
        bias[tp] = bih[r] + bhh[r];
    }
    float c = 0.f;

    __shared__ __align__(16) float gp[4][64][20];   // [wave][gate row][batch(+pad)]

    const int   xrow   = bg * 16 + lm;
    const float* xbase = x + (size_t)xrow * T_ * D_ + wv * 64;
    const u32 hoff_r = (u32)(bg * 16 + lm) * H_ + wv * 128;   // consumer fragment base
    const u32 hoff_w = (u32)(bg * 16 + pb) * H_ + gg * 16 + pj;

    for (int t = 0; t < T_; ++t) {
        f32x4 acc[4];
#pragma unroll
        for (int gt = 0; gt < 4; ++gt) acc[gt] = (f32x4){0.f, 0.f, 0.f, 0.f};

        // ---- x-part (independent of h; issued before the wait) ----
        const float* px = xbase + (size_t)t * D_;
#pragma unroll
        for (int kt = 0; kt < 2; ++kt) {
            const float* p = px + kt * 32 + lq * 8;
            f32x4 v0 = *(const f32x4*)p;
            f32x4 v1 = *(const f32x4*)(p + 4);
            bf16x8 ahi, alo;
#pragma unroll
            for (int e = 0; e < 4; ++e) {
                __bf16 h1 = (__bf16)v0[e];
                ahi[e] = h1; alo[e] = (__bf16)(v0[e] - (float)h1);
                __bf16 h2 = (__bf16)v1[e];
                ahi[e + 4] = h2; alo[e + 4] = (__bf16)(v1[e] - (float)h2);
            }
#pragma unroll
            for (int gt = 0; gt < 4; ++gt) {
                acc[gt] = __builtin_amdgcn_mfma_f32_16x16x32_bf16(ahi, wih_hi[kt][gt], acc[gt], 0, 0, 0);
                acc[gt] = __builtin_amdgcn_mfma_f32_16x16x32_bf16(ahi, wih_lo[kt][gt], acc[gt], 0, 0, 0);
                acc[gt] = __builtin_amdgcn_mfma_f32_16x16x32_bf16(alo, wih_hi[kt][gt], acc[gt], 0, 0, 0);
            }
        }

        // ---- h-part: wait for step t-1 producers, then sc1 loads -> MFMA ----
        if (t > 0) {
            if (tid == 0) {
                const u32 target = (u32)GG_ * (u32)t;
                while (__hip_atomic_load(&bar[bg * 32], __ATOMIC_RELAXED,
                                         __HIP_MEMORY_SCOPE_AGENT) < target)
                    __builtin_amdgcn_s_sleep(2);
            }
            __syncthreads();
            __atomic_signal_fence(__ATOMIC_SEQ_CST);

            const u32* hp = &g_h[(t - 1) & 1][hoff_r];
#pragma unroll
            for (int kt = 0; kt < 4; ++kt) {
                const u32* q = hp + kt * 32 + lq * 8;
                u64 q0 = __hip_atomic_load((const u64*)(q + 0), __ATOMIC_RELAXED, __HIP_MEMORY_SCOPE_AGENT);
                u64 q1 = __hip_atomic_load((const u64*)(q + 2), __ATOMIC_RELAXED, __HIP_MEMORY_SCOPE_AGENT);
                u64 q2 = __hip_atomic_load((const u64*)(q + 4), __ATOMIC_RELAXED, __HIP_MEMORY_SCOPE_AGENT);
                u64 q3 = __hip_atomic_load((const u64*)(q + 6), __ATOMIC_RELAXED, __HIP_MEMORY_SCOPE_AGENT);
                u32 wd[8] = {(u32)q0, (u32)(q0 >> 32), (u32)q1, (u32)(q1 >> 32),
                             (u32)q2, (u32)(q2 >> 32), (u32)q3, (u32)(q3 >> 32)};
                bf16x8 ahi, alo;
#pragma unroll
                for (int e = 0; e < 8; ++e) {
                    ahi[e] = __builtin_bit_cast(__bf16, (unsigned short)(wd[e] & 0xffffu));
                    alo[e] = __builtin_bit_cast(__bf16, (unsigned short)(wd[e] >> 16));
                }
#pragma unroll
                for (int gt = 0; gt < 4; ++gt) {
                    acc[gt] = __builtin_amdgcn_mfma_f32_16x16x32_bf16(ahi, whh_hi[kt][gt], acc[gt], 0, 0, 0);
                    acc[gt] = __builtin_amdgcn_mfma_f32_16x16x32_bf16(ahi, whh_lo[kt][gt], acc[gt], 0, 0, 0);
                    acc[gt] = __builtin_amdgcn_mfma_f32_16x16x32_bf16(alo, whh_hi[kt][gt], acc[gt], 0, 0, 0);
                }
            }
        }

        // ---- cross-wave K reduction via LDS ----
#pragma unroll
        for (int gt = 0; gt < 4; ++gt)
            *(f32x4*)&gp[wv][gt * 16 + lm][lq * 4] = acc[gt];   // C/D: col=lm(gate), row=lq*4+reg(batch)
        __syncthreads();

        float gate[4];
#pragma unroll
        for (int tp = 0; tp < 4; ++tp) {
            const int g = tp * 16 + pj;
            gate[tp] = gp[0][g][pb] + gp[1][g][pb] + gp[2][g][pb] + gp[3][g][pb] + bias[tp];
        }
        const float ig = sigmoidf_(gate[0]);
        const float fg = sigmoidf_(gate[1]);
        const float gv = tanhf_(gate[2]);
        const float og = sigmoidf_(gate[3]);
        c = fg * c + ig * gv;
        const float h = og * tanhf_(c);

        out[((size_t)t * B_ + bg * 16 + pb) * H_ + gg * 16 + pj] = h;

        const __bf16 hh = (__bf16)h;
        const __bf16 hl = (__bf16)(h - (float)hh);
        const u32 packed = (u32)__builtin_bit_cast(unsigned short, hh) |
                           ((u32)__builtin_bit_cast(unsigned short, hl) << 16);
        __hip_atomic_store(&g_h[t & 1][hoff_w], packed, __ATOMIC_RELAXED, __HIP_MEMORY_SCOPE_AGENT);

        // ---- signal: drain sc1 stores, then one relaxed atomicAdd per block ----
        if (t < T_ - 1) {
            __builtin_amdgcn_s_waitcnt(0);   // vmcnt(0) lgkmcnt(0): h stores at coherence point
            __syncthreads();
            if (tid == 0)
                __hip_atomic_fetch_add(&bar[bg * 32], 1u, __ATOMIC_RELAXED, __HIP_MEMORY_SCOPE_AGENT);
        }
    }
}

extern "C" void kernel_launch(void* const* d_in, const int* in_sizes, int n_in,
                              void* d_out, int out_size, void* d_ws, size_t ws_size,
                              hipStream_t stream) {
    const float* x   = (const float*)d_in[0];
    const float* Wih = (const float*)d_in[1];
    const float* Whh = (const float*)d_in[2];
    const float* bih = (const float*)d_in[3];
    const float* bhh = (const float*)d_in[4];
    float* out = (float*)d_out;
    u32* bar = (u32*)d_ws;

    hipMemsetAsync(d_ws, 0, 4096, stream);   // barrier counters (ws is poisoned to 0xAA)
    hipLaunchKernelGGL(lstm_persistent, dim3(GG_ * BG_), dim3(256), 0, stream,
                       x, Wih, Whh, bih, bhh, out, bar);
}